// Round 8
// baseline (145.914 us; speedup 1.0000x reference)
//
#include <hip/hip_runtime.h>

// GridEncoder (instant-NGP hash grid) forward, D=3, L=16, C=2, base_res=16,
// per_level_scale=2.0, log2_hashmap=19, align_corners=False.
//
// NUMERICS (verified R3-R6, absmax 4.8e-7): reference is JAX/XLA; jnp.exp2
// lowers to exp(x*ln2_f32) so scales are exact 16*2^l-1 EXCEPT
//   l=13 -> 131071.0625, l=15 -> 524286.75.
// pos = mul-round then add-round (no FMA); weights ((wx*wy)*wz) and the
// k=0..7 accumulation order kept op-by-op in f32 (__fmul_rn/__fadd_rn).
//
// Perf history: R4 level-major two-pass (934->314MB fetch). R5 pair-line
// float4 gathers via prime[0]==1 (8->6 L2 lookups/pt-lvl hashed). R6 XCD-
// pinned levels (blockIdx%8->XCD round-robin): each 4MiB table resident in
// exactly one XCD L2 -> FETCH 300->120MB (compulsory-only), time flat =>
// L2-REQUEST-RATE BOUND (~27 G req/s/XCD).
// R7: (a) dense-path pair loads (idx1=idx0+1 -> same float4 trick, 8->6),
//     (b) hoist all 8 gathers before consumption (VGPR 24 showed compiler
//         was interleaving, capping MLP), (c) 64-point transpose blocks.

constexpr int NLEV = 16;
constexpr int BLK  = 256;

template<bool TO_WS, bool PINNED>
__global__ __launch_bounds__(BLK) void grid_gather(
    const float* __restrict__ inputs,
    const float2* __restrict__ emb,
    const int* __restrict__ offsets,
    float2* __restrict__ dst,     // TO_WS: ws layout [l][b]; else out layout [b][l]
    int B, int chunks)
{
    // XLA-faithful scales (see header)
    const float SCALES[NLEV] = {
        15.f, 31.f, 63.f, 127.f, 255.f, 511.f, 1023.f, 2047.f,
        4095.f, 8191.f, 16383.f, 32767.f, 65535.f,
        131071.0625f,            // l=13 (XLA exp2 quirk)
        262143.f,
        524286.75f               // l=15 (XLA exp2 quirk)
    };

    int l, chunk;
    if (PINNED) {
        // grid = 16*chunks (divisible by 8). XCD = bid&7 (round-robin dispatch).
        int xcd = blockIdx.x & 7;
        int j   = blockIdx.x >> 3;            // [0, 2*chunks)
        if (j < chunks) { l = xcd;      chunk = j; }
        else            { l = 15 - xcd; chunk = j - chunks; }
    } else {
        l = blockIdx.x / chunks;
        chunk = blockIdx.x - l * chunks;
    }
    int b = chunk * BLK + threadIdx.x;
    if (b >= B) return;

    float x = inputs[(size_t)b * 3 + 0];
    float y = inputs[(size_t)b * 3 + 1];
    float z = inputs[(size_t)b * 3 + 2];

    int off0  = offsets[l];
    int hsize = offsets[l + 1] - off0;
    int res   = 16 << l;
    float scale = SCALES[l];
    long long r3 = (long long)res * res * res;
    bool use_hash = r3 > (long long)hsize;  // block-uniform (levels 3..15)
    uint32_t uh   = (uint32_t)hsize;
    bool     pow2 = (uh & (uh - 1u)) == 0u;

    // pos: mul-round then add-round, exactly as XLA's two elementwise ops
    float px = __fadd_rn(__fmul_rn(x, scale), 0.5f);
    float py = __fadd_rn(__fmul_rn(y, scale), 0.5f);
    float pz = __fadd_rn(__fmul_rn(z, scale), 0.5f);
    float gx = floorf(px), gy = floorf(py), gz = floorf(pz);
    float fx = __fsub_rn(px, gx), fy = __fsub_rn(py, gy), fz = __fsub_rn(pz, gz);
    int pgx = (int)gx, pgy = (int)gy, pgz = (int)gz;
    float omx = __fsub_rn(1.0f, fx), omy = __fsub_rn(1.0f, fy), omz = __fsub_rn(1.0f, fz);

    float r0 = 0.0f, r1 = 0.0f;
    const float2* tab = emb + (size_t)off0;   // 64B-aligned (off0 % 8 == 0)

    if (use_hash && pow2) {
        const uint32_t mask = uh - 1u;
        // phase 1: all 8 indices
        uint32_t i0[4], i1[4];
        #pragma unroll
        for (int k2 = 0; k2 < 4; ++k2) {
            const int by = k2 & 1, bz = (k2 >> 1) & 1;
            uint32_t m = ((uint32_t)(pgy + by) * 2654435761u)
                       ^ ((uint32_t)(pgz + bz) * 805459861u);
            i0[k2] = (((uint32_t)pgx)       ^ m) & mask;   // corner bx=0
            i1[k2] = (((uint32_t)(pgx + 1)) ^ m) & mask;   // corner bx=1
        }
        // phase 2: all 8 pair-line loads in flight (MLP)
        float4 q0[4], q1[4];
        #pragma unroll
        for (int k2 = 0; k2 < 4; ++k2) {
            q0[k2] = *(const float4*)(tab + (i0[k2] & ~1u));
            q1[k2] = *(const float4*)(tab + (i1[k2] & ~1u));
        }
        // phase 3: consume in reference order k = 2*k2, 2*k2+1
        #pragma unroll
        for (int k2 = 0; k2 < 4; ++k2) {
            const int by = k2 & 1, bz = (k2 >> 1) & 1;
            float2 v0 = (i0[k2] & 1u) ? make_float2(q0[k2].z, q0[k2].w)
                                      : make_float2(q0[k2].x, q0[k2].y);
            float2 v1 = (i1[k2] & 1u) ? make_float2(q1[k2].z, q1[k2].w)
                                      : make_float2(q1[k2].x, q1[k2].y);
            float wy = by ? fy : omy;
            float wz = bz ? fz : omz;
            float w0 = __fmul_rn(__fmul_rn(omx, wy), wz);  // ((wx*wy)*wz)
            float w1 = __fmul_rn(__fmul_rn(fx,  wy), wz);
            r0 = __fadd_rn(r0, __fmul_rn(w0, v0.x));
            r1 = __fadd_rn(r1, __fmul_rn(w0, v0.y));
            r0 = __fadd_rn(r0, __fmul_rn(w1, v1.x));
            r1 = __fadd_rn(r1, __fmul_rn(w1, v1.y));
        }
    } else {
        // dense levels 0..2: corner pair bx=0,1 -> di and di+1 (pre-mod),
        // same pair-line float4 trick. Mirrors reference's % hsize exactly.
        uint32_t i0[4], i1[4];
        #pragma unroll
        for (int k2 = 0; k2 < 4; ++k2) {
            const int by = k2 & 1, bz = (k2 >> 1) & 1;
            int di0 = pgx + (pgy + by) * res + (pgz + bz) * res * res;
            i0[k2] = (uint32_t)(di0 % hsize);
            i1[k2] = (uint32_t)((di0 + 1) % hsize);
        }
        float4 q0[4], q1[4];
        #pragma unroll
        for (int k2 = 0; k2 < 4; ++k2) {
            q0[k2] = *(const float4*)(tab + (i0[k2] & ~1u));
            q1[k2] = *(const float4*)(tab + (i1[k2] & ~1u));
        }
        #pragma unroll
        for (int k2 = 0; k2 < 4; ++k2) {
            const int by = k2 & 1, bz = (k2 >> 1) & 1;
            float2 v0 = (i0[k2] & 1u) ? make_float2(q0[k2].z, q0[k2].w)
                                      : make_float2(q0[k2].x, q0[k2].y);
            float2 v1 = (i1[k2] & 1u) ? make_float2(q1[k2].z, q1[k2].w)
                                      : make_float2(q1[k2].x, q1[k2].y);
            float wy = by ? fy : omy;
            float wz = bz ? fz : omz;
            float w0 = __fmul_rn(__fmul_rn(omx, wy), wz);
            float w1 = __fmul_rn(__fmul_rn(fx,  wy), wz);
            r0 = __fadd_rn(r0, __fmul_rn(w0, v0.x));
            r1 = __fadd_rn(r1, __fmul_rn(w0, v0.y));
            r0 = __fadd_rn(r0, __fmul_rn(w1, v1.x));
            r1 = __fadd_rn(r1, __fmul_rn(w1, v1.y));
        }
    }

    if (TO_WS)
        dst[(size_t)l * B + b] = make_float2(r0, r1);      // coalesced
    else
        dst[(size_t)b * NLEV + l] = make_float2(r0, r1);   // strided fallback
}

// ws [l][b] (float2, l-major) -> out [b][l*2+c]; LDS-staged, 64 points/block,
// 8KB contiguous global write per block.
__global__ __launch_bounds__(256) void transpose_lds(
    const float4* __restrict__ ws4,   // ws viewed as float4: [NLEV][B/2]
    float4* __restrict__ out4,        // out viewed as float4: [B][8]
    int B)
{
    __shared__ float2 lds[64][17];    // +1 pad breaks pow2 bank stride
    int halfB = B >> 1;               // B even
    int b0 = blockIdx.x * 64;         // 64 points per block
    int t = threadIdx.x;

    // read: 16 levels x 32 point-pairs = 512 float4, 2 per thread
    #pragma unroll
    for (int rep = 0; rep < 2; ++rep) {
        int idx = t + rep * 256;
        int l = idx >> 5, p = idx & 31;
        int gp = (b0 >> 1) + p;
        if (gp < halfB) {
            float4 q = ws4[(size_t)l * halfB + gp];   // 512B contiguous per level
            lds[2 * p][l]     = make_float2(q.x, q.y);
            lds[2 * p + 1][l] = make_float2(q.z, q.w);
        }
    }
    __syncthreads();

    // write: 64 points x 8 float4 = 512, 2 per thread, contiguous per block
    #pragma unroll
    for (int rep = 0; rep < 2; ++rep) {
        int idx = t + rep * 256;
        int pt = idx >> 3, c = idx & 7;
        int gb = b0 + pt;
        if (gb < B) {
            float2 a  = lds[pt][2 * c];
            float2 b2 = lds[pt][2 * c + 1];
            out4[(size_t)gb * 8 + c] = make_float4(a.x, a.y, b2.x, b2.y);
        }
    }
}

// fallback (odd B): 1 point/thread, per-lane-contiguous writes
__global__ __launch_bounds__(256) void transpose_out1(
    const float2* __restrict__ ws,
    float2* __restrict__ out,
    int B)
{
    int b = blockIdx.x * 256 + threadIdx.x;
    if (b >= B) return;
    float2 v[NLEV];
    #pragma unroll
    for (int l = 0; l < NLEV; ++l)
        v[l] = ws[(size_t)l * B + b];
    float4* o = (float4*)(out + (size_t)b * NLEV);
    #pragma unroll
    for (int i = 0; i < 8; ++i)
        o[i] = make_float4(v[2*i].x, v[2*i].y, v[2*i+1].x, v[2*i+1].y);
}

extern "C" void kernel_launch(void* const* d_in, const int* in_sizes, int n_in,
                              void* d_out, int out_size, void* d_ws, size_t ws_size,
                              hipStream_t stream) {
    const float*  inputs  = (const float*)d_in[0];
    const float2* emb     = (const float2*)d_in[1];
    const int*    offsets = (const int*)d_in[2];
    float2*       out     = (float2*)d_out;
    int B = in_sizes[0] / 3;
    int chunks = (B + BLK - 1) / BLK;
    int grid = NLEV * chunks;

    bool use_ws = ws_size >= (size_t)B * NLEV * sizeof(float2);
    if (use_ws) {
        float2* ws = (float2*)d_ws;
        hipLaunchKernelGGL((grid_gather<true, true>), dim3(grid), dim3(BLK), 0, stream,
                           inputs, emb, offsets, ws, B, chunks);
        if ((B & 1) == 0) {
            hipLaunchKernelGGL(transpose_lds, dim3((B + 63) / 64), dim3(256), 0, stream,
                               (const float4*)ws, (float4*)out, B);
        } else {
            hipLaunchKernelGGL(transpose_out1, dim3((B + 255) / 256), dim3(256), 0, stream,
                               ws, out, B);
        }
    } else {
        hipLaunchKernelGGL((grid_gather<false, false>), dim3(grid), dim3(BLK), 0, stream,
                           inputs, emb, offsets, out, B, chunks);
    }
}

// Round 9
// 125.159 us; speedup vs baseline: 1.1658x; 1.1658x over previous
//
#include <hip/hip_runtime.h>

// GridEncoder (instant-NGP hash grid) forward, D=3, L=16, C=2, base_res=16,
// per_level_scale=2.0, log2_hashmap=19, align_corners=False.
//
// NUMERICS (verified R3-R8, absmax 4.8e-7): reference is JAX/XLA; jnp.exp2
// lowers to exp(x*ln2_f32) so scales are exact 16*2^l-1 EXCEPT
//   l=13 -> 131071.0625, l=15 -> 524286.75.
// pos = mul-round then add-round (no FMA); weights ((wx*wy)*wz) and the
// k=0..7 accumulation order kept op-by-op in f32 (__fmul_rn/__fadd_rn).
//
// Perf history:
//  R4 level-major two-pass: FETCH 934->314MB, 267->176us.
//  R5 pair-line float4 gathers (prime[0]==1): hashed 8->6 L2 req/pt. 156us.
//  R6 XCD-pinned levels (blockIdx%8 -> XCD round-robin): each 4MiB table
//     resident in ONE XCD L2 -> FETCH 300->120MB (compulsory), 123us.
//     => L2-REQUEST-RATE BOUND (~225 G req/s device-wide).
//  R7 MLP-hoist attempt REGRESSED (146us): compiler re-interleaved (VGPR 28),
//     restructuring was pure scheduling noise. REVERTED here.
//  R8(this): R6 hashed path verbatim + dense pair-loads inside the same
//     interleaved per-k2 structure (dense 8->6 req/pt, total req -5.4%).

constexpr int NLEV = 16;
constexpr int BLK  = 256;

template<bool TO_WS, bool PINNED>
__global__ __launch_bounds__(BLK) void grid_gather(
    const float* __restrict__ inputs,
    const float2* __restrict__ emb,
    const int* __restrict__ offsets,
    float2* __restrict__ dst,     // TO_WS: ws layout [l][b]; else out layout [b][l]
    int B, int chunks)
{
    // XLA-faithful scales (see header)
    const float SCALES[NLEV] = {
        15.f, 31.f, 63.f, 127.f, 255.f, 511.f, 1023.f, 2047.f,
        4095.f, 8191.f, 16383.f, 32767.f, 65535.f,
        131071.0625f,            // l=13 (XLA exp2 quirk)
        262143.f,
        524286.75f               // l=15 (XLA exp2 quirk)
    };

    int l, chunk;
    if (PINNED) {
        // grid = 16*chunks (divisible by 8). XCD = bid&7 (round-robin dispatch).
        int xcd = blockIdx.x & 7;
        int j   = blockIdx.x >> 3;            // [0, 2*chunks)
        if (j < chunks) { l = xcd;      chunk = j; }
        else            { l = 15 - xcd; chunk = j - chunks; }
    } else {
        l = blockIdx.x / chunks;
        chunk = blockIdx.x - l * chunks;
    }
    int b = chunk * BLK + threadIdx.x;
    if (b >= B) return;

    float x = inputs[(size_t)b * 3 + 0];
    float y = inputs[(size_t)b * 3 + 1];
    float z = inputs[(size_t)b * 3 + 2];

    int off0  = offsets[l];
    int hsize = offsets[l + 1] - off0;
    int res   = 16 << l;
    float scale = SCALES[l];
    long long r3 = (long long)res * res * res;
    bool use_hash = r3 > (long long)hsize;  // block-uniform (levels 3..15)
    uint32_t uh   = (uint32_t)hsize;
    bool     pow2 = (uh & (uh - 1u)) == 0u;

    // pos: mul-round then add-round, exactly as XLA's two elementwise ops
    float px = __fadd_rn(__fmul_rn(x, scale), 0.5f);
    float py = __fadd_rn(__fmul_rn(y, scale), 0.5f);
    float pz = __fadd_rn(__fmul_rn(z, scale), 0.5f);
    float gx = floorf(px), gy = floorf(py), gz = floorf(pz);
    float fx = __fsub_rn(px, gx), fy = __fsub_rn(py, gy), fz = __fsub_rn(pz, gz);
    int pgx = (int)gx, pgy = (int)gy, pgz = (int)gz;
    float omx = __fsub_rn(1.0f, fx), omy = __fsub_rn(1.0f, fy), omz = __fsub_rn(1.0f, fz);

    float r0 = 0.0f, r1 = 0.0f;
    const float2* tab = emb + (size_t)off0;   // 64B-aligned (off0 % 8 == 0)

    if (use_hash && pow2) {
        const uint32_t mask = uh - 1u;
        #pragma unroll
        for (int k2 = 0; k2 < 4; ++k2) {
            const int by = k2 & 1, bz = (k2 >> 1) & 1;
            uint32_t m = ((uint32_t)(pgy + by) * 2654435761u)
                       ^ ((uint32_t)(pgz + bz) * 805459861u);
            uint32_t i0 = ((uint32_t)pgx ^ m) & mask;        // corner bx=0
            uint32_t i1 = ((uint32_t)(pgx + 1) ^ m) & mask;  // corner bx=1
            // pair-line loads, 16B aligned; for even pgx both hit one line
            float4 q0 = *(const float4*)(tab + (i0 & ~1u));
            float4 q1 = *(const float4*)(tab + (i1 & ~1u));
            float2 v0 = (i0 & 1u) ? make_float2(q0.z, q0.w) : make_float2(q0.x, q0.y);
            float2 v1 = (i1 & 1u) ? make_float2(q1.z, q1.w) : make_float2(q1.x, q1.y);
            float wy = by ? fy : omy;
            float wz = bz ? fz : omz;
            float w0 = __fmul_rn(__fmul_rn(omx, wy), wz);  // ((wx*wy)*wz) order
            float w1 = __fmul_rn(__fmul_rn(fx,  wy), wz);
            // accumulation order == reference k = 2*k2, 2*k2+1
            r0 = __fadd_rn(r0, __fmul_rn(w0, v0.x));
            r1 = __fadd_rn(r1, __fmul_rn(w0, v0.y));
            r0 = __fadd_rn(r0, __fmul_rn(w1, v1.x));
            r1 = __fadd_rn(r1, __fmul_rn(w1, v1.y));
        }
    } else {
        // dense levels 0..2: corner bx=1 index = di0+1 (pre-mod) -> same
        // pair-line trick, in the SAME interleaved per-k2 structure as above.
        #pragma unroll
        for (int k2 = 0; k2 < 4; ++k2) {
            const int by = k2 & 1, bz = (k2 >> 1) & 1;
            int di0 = pgx + (pgy + by) * res + (pgz + bz) * res * res;
            uint32_t i0 = (uint32_t)(di0 % hsize);          // mirrors reference %
            uint32_t i1 = (uint32_t)((di0 + 1) % hsize);
            float4 q0 = *(const float4*)(tab + (i0 & ~1u));
            float4 q1 = *(const float4*)(tab + (i1 & ~1u));
            float2 v0 = (i0 & 1u) ? make_float2(q0.z, q0.w) : make_float2(q0.x, q0.y);
            float2 v1 = (i1 & 1u) ? make_float2(q1.z, q1.w) : make_float2(q1.x, q1.y);
            float wy = by ? fy : omy;
            float wz = bz ? fz : omz;
            float w0 = __fmul_rn(__fmul_rn(omx, wy), wz);
            float w1 = __fmul_rn(__fmul_rn(fx,  wy), wz);
            r0 = __fadd_rn(r0, __fmul_rn(w0, v0.x));
            r1 = __fadd_rn(r1, __fmul_rn(w0, v0.y));
            r0 = __fadd_rn(r0, __fmul_rn(w1, v1.x));
            r1 = __fadd_rn(r1, __fmul_rn(w1, v1.y));
        }
    }

    if (TO_WS)
        dst[(size_t)l * B + b] = make_float2(r0, r1);      // coalesced
    else
        dst[(size_t)b * NLEV + l] = make_float2(r0, r1);   // strided fallback
}

// ws [l][b] (float2, l-major) -> out [b][l*2+c]; LDS-staged, 64 points/block,
// 8KB contiguous global write per block.
__global__ __launch_bounds__(256) void transpose_lds(
    const float4* __restrict__ ws4,   // ws viewed as float4: [NLEV][B/2]
    float4* __restrict__ out4,        // out viewed as float4: [B][8]
    int B)
{
    __shared__ float2 lds[64][17];    // +1 pad breaks pow2 bank stride
    int halfB = B >> 1;               // B even
    int b0 = blockIdx.x * 64;         // 64 points per block
    int t = threadIdx.x;

    // read: 16 levels x 32 point-pairs = 512 float4, 2 per thread
    #pragma unroll
    for (int rep = 0; rep < 2; ++rep) {
        int idx = t + rep * 256;
        int l = idx >> 5, p = idx & 31;
        int gp = (b0 >> 1) + p;
        if (gp < halfB) {
            float4 q = ws4[(size_t)l * halfB + gp];   // 512B contiguous per level
            lds[2 * p][l]     = make_float2(q.x, q.y);
            lds[2 * p + 1][l] = make_float2(q.z, q.w);
        }
    }
    __syncthreads();

    // write: 64 points x 8 float4 = 512, 2 per thread, contiguous per block
    #pragma unroll
    for (int rep = 0; rep < 2; ++rep) {
        int idx = t + rep * 256;
        int pt = idx >> 3, c = idx & 7;
        int gb = b0 + pt;
        if (gb < B) {
            float2 a  = lds[pt][2 * c];
            float2 b2 = lds[pt][2 * c + 1];
            out4[(size_t)gb * 8 + c] = make_float4(a.x, a.y, b2.x, b2.y);
        }
    }
}

// fallback (odd B): 1 point/thread, per-lane-contiguous writes
__global__ __launch_bounds__(256) void transpose_out1(
    const float2* __restrict__ ws,
    float2* __restrict__ out,
    int B)
{
    int b = blockIdx.x * 256 + threadIdx.x;
    if (b >= B) return;
    float2 v[NLEV];
    #pragma unroll
    for (int l = 0; l < NLEV; ++l)
        v[l] = ws[(size_t)l * B + b];
    float4* o = (float4*)(out + (size_t)b * NLEV);
    #pragma unroll
    for (int i = 0; i < 8; ++i)
        o[i] = make_float4(v[2*i].x, v[2*i].y, v[2*i+1].x, v[2*i+1].y);
}

extern "C" void kernel_launch(void* const* d_in, const int* in_sizes, int n_in,
                              void* d_out, int out_size, void* d_ws, size_t ws_size,
                              hipStream_t stream) {
    const float*  inputs  = (const float*)d_in[0];
    const float2* emb     = (const float2*)d_in[1];
    const int*    offsets = (const int*)d_in[2];
    float2*       out     = (float2*)d_out;
    int B = in_sizes[0] / 3;
    int chunks = (B + BLK - 1) / BLK;
    int grid = NLEV * chunks;

    bool use_ws = ws_size >= (size_t)B * NLEV * sizeof(float2);
    if (use_ws) {
        float2* ws = (float2*)d_ws;
        hipLaunchKernelGGL((grid_gather<true, true>), dim3(grid), dim3(BLK), 0, stream,
                           inputs, emb, offsets, ws, B, chunks);
        if ((B & 1) == 0) {
            hipLaunchKernelGGL(transpose_lds, dim3((B + 63) / 64), dim3(256), 0, stream,
                               (const float4*)ws, (float4*)out, B);
        } else {
            hipLaunchKernelGGL(transpose_out1, dim3((B + 255) / 256), dim3(256), 0, stream,
                               ws, out, B);
        }
    } else {
        hipLaunchKernelGGL((grid_gather<false, false>), dim3(grid), dim3(BLK), 0, stream,
                           inputs, emb, offsets, out, B, chunks);
    }
}